// Round 20
// baseline (52.077 us; speedup 1.0000x reference)
//
#include <hip/hip_runtime.h>

#define DIMS 128
#define KTOP 16
#define SMAX 2048     // max MAXG supported by top-k kernel
#define SLICE 64      // candidates per score slice
#define CK 64         // s_keyT row stride in dwords (unpadded; 2-way = free)
#define QT 32         // queries per chunk (one chunk covers cnt<=32)
#define CQ 32         // s_qT row stride in dwords
#define NTHR 256      // 4 waves: 2 stage keys, 2 stage queries, all compute

__device__ __forceinline__ unsigned long long packsim(float v, int g) {
    unsigned u = __float_as_uint(v);
    u = (u & 0x80000000u) ? ~u : (u | 0x80000000u);
    return ((unsigned long long)u << 32) | (unsigned)(0xFFFFFFFFu - (unsigned)g);
}

// ------- Kernel 0: zero + bucket queries, single block (r5-proven) -------
__global__ __launch_bounds__(1024)
void bucket_kernel(const int* __restrict__ hard_assign,
                   int* __restrict__ qcount, int* __restrict__ qlist, int B, int P)
{
    const int t = threadIdx.x;
    for (int i = t; i < P; i += 1024) qcount[i] = 0;
    __syncthreads();
    for (int b = t; b < B; b += 1024) {
        const int p = hard_assign[b];
        const int slot = atomicAdd(&qcount[p], 1);
        qlist[(size_t)p * B + slot] = b;
    }
}

// ---- Kernel 1: r16 GEMM core + T14 async-stage: 2 slices/block, slice-B keys
// prefetched to registers during slice-A compute (issue-early / write-late). ----
__global__ __launch_bounds__(NTHR)
void score_kernel(const float* __restrict__ query,
                  const float* __restrict__ keys,
                  const int*   __restrict__ cached_groups,
                  const int*   __restrict__ qcount,
                  const int*   __restrict__ qlist,
                  float* __restrict__ sims,
                  int B, int N, int MAXG, int nslice, int npair)
{
    __shared__ float s_keyT[DIMS * CK];   // 32 KB, [d][c]
    __shared__ float s_qT[DIMS * CQ];     // 16 KB, [d][q]
    __shared__ float s_inv[SLICE];
    __shared__ int   s_g[SLICE];
    __shared__ int   s_qb[QT];

    const int p  = blockIdx.x / npair;
    const int pr = blockIdx.x % npair;
    const int s0 = pr * 2;
    const int s1 = s0 + 1;
    const int cnt = qcount[p];
    if (cnt == 0) return;

    const int t = threadIdx.x;
    const int base0 = s0 * SLICE;
    const int base1 = s1 * SLICE;
    const bool have1 = (s1 < nslice);
    const int* gp = cached_groups + (size_t)p * MAXG;
    const int* ql = qlist + (size_t)p * B;

    const int r    = t >> 1;              // staging: candidate row
    const int half = t & 1;               // staging: dim half

    // slice-B candidate id loaded up front (latency overlaps slice-A staging)
    int cand1 = -1;
    if (t < 128 && have1 && base1 + r < MAXG) cand1 = gp[base1 + r];

    // ---- parallel staging: waves 0-1 keys(A), waves 2-3 query chunk 0 ----
    if (t < 128) {
        const int cand = (base0 + r < MAXG) ? gp[base0 + r] : -1;
        if (half == 0) s_g[r] = cand;
        const int sf = cand < 0 ? 0 : (cand > N - 1 ? N - 1 : cand);
        const float* kr = keys + (size_t)sf * DIMS + half * 64;
        float4 v[16];
        #pragma unroll
        for (int i = 0; i < 16; ++i)
            v[i] = *(const float4*)(kr + i * 4);
        float ks = 0.0f;
        #pragma unroll
        for (int i = 0; i < 16; ++i) {
            const int d = half * 64 + i * 4;
            ks += v[i].x * v[i].x + v[i].y * v[i].y
                + v[i].z * v[i].z + v[i].w * v[i].w;
            s_keyT[(d + 0) * CK + r] = v[i].x;
            s_keyT[(d + 1) * CK + r] = v[i].y;
            s_keyT[(d + 2) * CK + r] = v[i].z;
            s_keyT[(d + 3) * CK + r] = v[i].w;
        }
        ks += __shfl_xor(ks, 1, 64);
        if (half == 0) s_inv[r] = 1.0f / fmaxf(sqrtf(ks), 1e-12f);
    } else {
        const int tq   = t - 128;
        const int q    = tq & 31;
        const int dblk = tq >> 5;
        const int sq   = ql[(q < cnt) ? q : (cnt - 1)];
        if (dblk == 0) s_qb[q] = sq;
        const float* qr = query + (size_t)sq * DIMS + dblk * 32;
        #pragma unroll
        for (int i = 0; i < 8; ++i) {
            const float4 v = *(const float4*)(qr + i * 4);
            const int d = dblk * 32 + i * 4;
            s_qT[(d + 0) * CQ + q] = v.x;
            s_qT[(d + 1) * CQ + q] = v.y;
            s_qT[(d + 2) * CQ + q] = v.z;
            s_qT[(d + 3) * CQ + q] = v.w;
        }
    }
    __syncthreads();

    // ---- T14 issue-early: slice-B key rows -> registers, BEFORE compute A.
    // The memory fence pins the issue point; vmcnt waits land after compute A.
    float4 pv[16];
    {
        const int sf1 = cand1 < 0 ? 0 : (cand1 > N - 1 ? N - 1 : cand1);
        if (t < 128 && have1) {
            const float* kr1 = keys + (size_t)sf1 * DIMS + half * 64;
            #pragma unroll
            for (int i = 0; i < 16; ++i)
                pv[i] = *(const float4*)(kr1 + i * 4);
        }
    }
    asm volatile("" ::: "memory");

    const int q0 = (t >> 4) * 2;          // 0,2,..,30
    const int c0 = (t & 15) * 4;          // 0,4,..,60

    auto compute_slice = [&](const int base) {
        for (int qbase = 0; ; ) {
            float acc[2][4];
            #pragma unroll
            for (int a = 0; a < 2; ++a)
                #pragma unroll
                for (int bb = 0; bb < 4; ++bb) acc[a][bb] = 0.0f;

            // A-read: b64 broadcast; B-read: b128 2-way (free)
            #pragma unroll 8
            for (int k = 0; k < DIMS; ++k) {
                const float2 aq = *(const float2*)&s_qT[k * CQ + q0];
                const float4 bk = *(const float4*)&s_keyT[k * CK + c0];
                acc[0][0] += aq.x * bk.x; acc[0][1] += aq.x * bk.y;
                acc[0][2] += aq.x * bk.z; acc[0][3] += aq.x * bk.w;
                acc[1][0] += aq.y * bk.x; acc[1][1] += aq.y * bk.y;
                acc[1][2] += aq.y * bk.z; acc[1][3] += aq.y * bk.w;
            }

            const float4 inv = *(const float4*)&s_inv[c0];
            const int4   gv  = *(const int4*)&s_g[c0];
            #pragma unroll
            for (int qi = 0; qi < 2; ++qi) {
                const int ii = qbase + q0 + qi;
                if (ii < cnt) {
                    const int b = s_qb[q0 + qi];
                    float4 o;
                    o.x = (gv.x >= 0) ? acc[qi][0] * inv.x : -1.0e9f;
                    o.y = (gv.y >= 0) ? acc[qi][1] * inv.y : -1.0e9f;
                    o.z = (gv.z >= 0) ? acc[qi][2] * inv.z : -1.0e9f;
                    o.w = (gv.w >= 0) ? acc[qi][3] * inv.w : -1.0e9f;
                    float* dst = sims + (size_t)b * MAXG + base + c0;
                    if (base + c0 + 3 < MAXG) {
                        *(float4*)dst = o;
                    } else {
                        if (base + c0 + 0 < MAXG) dst[0] = o.x;
                        if (base + c0 + 1 < MAXG) dst[1] = o.y;
                        if (base + c0 + 2 < MAXG) dst[2] = o.z;
                    }
                }
            }

            qbase += QT;
            if (qbase >= cnt) break;      // common case: single chunk

            __syncthreads();
            if (t >= 128) {               // rare (cnt > 32): restage next chunk
                const int tq   = t - 128;
                const int q    = tq & 31;
                const int dblk = tq >> 5;
                const int ii   = qbase + q;
                const int sq   = ql[(ii < cnt) ? ii : (cnt - 1)];
                if (dblk == 0) s_qb[q] = sq;
                const float* qr = query + (size_t)sq * DIMS + dblk * 32;
                #pragma unroll
                for (int i = 0; i < 8; ++i) {
                    const float4 v = *(const float4*)(qr + i * 4);
                    const int d = dblk * 32 + i * 4;
                    s_qT[(d + 0) * CQ + q] = v.x;
                    s_qT[(d + 1) * CQ + q] = v.y;
                    s_qT[(d + 2) * CQ + q] = v.z;
                    s_qT[(d + 3) * CQ + q] = v.w;
                }
            }
            __syncthreads();
        }
    };

    compute_slice(base0);

    if (!have1) return;
    __syncthreads();   // slice-A reads done; prefetch loads have landed by now

    // ---- write-late: slice-B keys regs -> LDS (same sum order as slice A) ----
    if (t < 128) {
        if (half == 0) s_g[r] = cand1;
        float ks = 0.0f;
        #pragma unroll
        for (int i = 0; i < 16; ++i) {
            const int d = half * 64 + i * 4;
            ks += pv[i].x * pv[i].x + pv[i].y * pv[i].y
                + pv[i].z * pv[i].z + pv[i].w * pv[i].w;
            s_keyT[(d + 0) * CK + r] = pv[i].x;
            s_keyT[(d + 1) * CK + r] = pv[i].y;
            s_keyT[(d + 2) * CK + r] = pv[i].z;
            s_keyT[(d + 3) * CK + r] = pv[i].w;
        }
        ks += __shfl_xor(ks, 1, 64);
        if (half == 0) s_inv[r] = 1.0f / fmaxf(sqrtf(ks), 1e-12f);
    } else if (cnt > QT) {
        // q-chunk 0 was clobbered by slice-A's chunk loop: restage it
        const int tq   = t - 128;
        const int q    = tq & 31;
        const int dblk = tq >> 5;
        const int sq   = ql[(q < cnt) ? q : (cnt - 1)];
        if (dblk == 0) s_qb[q] = sq;
        const float* qr = query + (size_t)sq * DIMS + dblk * 32;
        #pragma unroll
        for (int i = 0; i < 8; ++i) {
            const float4 v = *(const float4*)(qr + i * 4);
            const int d = dblk * 32 + i * 4;
            s_qT[(d + 0) * CQ + q] = v.x;
            s_qT[(d + 1) * CQ + q] = v.y;
            s_qT[(d + 2) * CQ + q] = v.z;
            s_qT[(d + 3) * CQ + q] = v.w;
        }
    }
    __syncthreads();

    compute_slice(base1);
}

// ---------------- Kernel 2: top-16 per query + output gather ----------------
#define CASW(x,y) { if ((x) < (y)) { const unsigned long long _t = (x); (x) = (y); (y) = _t; } }

__global__ __launch_bounds__(256)
void topk_gather_kernel(const float* __restrict__ keys,
                        const float* __restrict__ vals,
                        const float* __restrict__ labels,
                        const int*   __restrict__ hard_assign,
                        const int*   __restrict__ cached_groups,
                        const int*   __restrict__ group_sizes,
                        const float* __restrict__ sims,
                        float* __restrict__ out,
                        int B, int MAXG)
{
    const int b = blockIdx.x, t = threadIdx.x;
    const int lane = t & 63, w = t >> 6;
    const int sub = t & 15, cg = t >> 4;

    __shared__ unsigned long long s_merge[64];
    __shared__ int s_wing[KTOP];

    const int p = hard_assign[b];
    const int grpsz = group_sizes[p];
    const bool normal = (grpsz >= KTOP);
    const int* gptr = cached_groups + (size_t)p * MAXG;
    const float* simrow = sims + (size_t)b * MAXG;

    // phase A: per-wave top-16 of 512; lane owns 8 consecutive -> 2 b128 loads
    unsigned long long k0, k1, k2, k3, k4, k5, k6, k7;
    {
        const int g0 = w * (SMAX / 4) + lane * 8;
        if (g0 + 7 < MAXG) {
            const float4 va = *(const float4*)(simrow + g0);
            const float4 vb = *(const float4*)(simrow + g0 + 4);
            k0 = packsim(va.x, g0 + 0); k1 = packsim(va.y, g0 + 1);
            k2 = packsim(va.z, g0 + 2); k3 = packsim(va.w, g0 + 3);
            k4 = packsim(vb.x, g0 + 4); k5 = packsim(vb.y, g0 + 5);
            k6 = packsim(vb.z, g0 + 6); k7 = packsim(vb.w, g0 + 7);
        } else {
            #define LDK(j) packsim((g0 + (j) < MAXG) ? simrow[g0 + (j)] : -3.0e38f, g0 + (j))
            k0 = LDK(0); k1 = LDK(1); k2 = LDK(2); k3 = LDK(3);
            k4 = LDK(4); k5 = LDK(5); k6 = LDK(6); k7 = LDK(7);
            #undef LDK
        }
    }
    // Batcher odd-even mergesort, 19 comparators, descending
    CASW(k0,k1) CASW(k2,k3) CASW(k4,k5) CASW(k6,k7)
    CASW(k0,k2) CASW(k1,k3) CASW(k4,k6) CASW(k5,k7)
    CASW(k1,k2) CASW(k5,k6)
    CASW(k0,k4) CASW(k1,k5) CASW(k2,k6) CASW(k3,k7)
    CASW(k2,k4) CASW(k3,k5)
    CASW(k1,k2) CASW(k3,k4) CASW(k5,k6)

    #pragma unroll 1
    for (int r = 0; r < KTOP; ++r) {
        unsigned long long wm = k0;
        #pragma unroll
        for (int off = 1; off < 64; off <<= 1) {
            const unsigned long long o = __shfl_xor(wm, off, 64);
            wm = (o > wm) ? o : wm;
        }
        if (lane == 0) s_merge[w * KTOP + r] = wm;
        if (k0 == wm) {                  // unique keys -> exactly one winner
            k0 = k1; k1 = k2; k2 = k3; k3 = k4;
            k4 = k5; k5 = k6; k6 = k7; k7 = 0ull;
        }
    }
    __syncthreads();

    // phase B: wave 0 bitonic-sorts the 64 survivors; rank r at lane 63-r
    if (w == 0) {
        unsigned long long u = s_merge[lane];
        #pragma unroll
        for (int k = 2; k <= 64; k <<= 1) {
            #pragma unroll
            for (int j = k >> 1; j > 0; j >>= 1) {
                const unsigned long long o = __shfl_xor(u, j, 64);
                const bool low = (lane & j) == 0;
                const bool asc = (lane & k) == 0;
                const unsigned long long mn = (u < o) ? u : o;
                const unsigned long long mx = (u < o) ? o : u;
                u = (low == asc) ? mn : mx;
            }
        }
        if (lane >= 64 - KTOP)
            s_wing[63 - lane] = (int)(0xFFFFFFFFu - (unsigned)(u & 0xFFFFFFFFull));
    }
    __syncthreads();

    // outputs: group cg handles winner #cg
    const int g    = s_wing[cg];
    const int cand = gptr[g];
    const int idx  = cand < 0 ? 0 : cand;

    const size_t BK = (size_t)B * KTOP;
    float* out_nk = out;
    float* out_nv = out + BK * DIMS;
    float* out_nl = out + 2 * BK * DIMS;
    float* out_id = out_nl + BK;

    const size_t od = ((size_t)b * KTOP + cg) * DIMS + sub * 8;
    if (normal) {
        const float* kr = keys + (size_t)idx * DIMS + sub * 8;
        const float* vr = vals + (size_t)idx * DIMS + sub * 8;
        *(float4*)(out_nk + od)     = *(const float4*)(kr);
        *(float4*)(out_nk + od + 4) = *(const float4*)(kr + 4);
        *(float4*)(out_nv + od)     = *(const float4*)(vr);
        *(float4*)(out_nv + od + 4) = *(const float4*)(vr + 4);
        if (sub == 0) {
            out_nl[(size_t)b * KTOP + cg] = labels[idx];
            out_id[(size_t)b * KTOP + cg] = (float)idx;
        }
    } else {
        const float4 z = make_float4(0.f, 0.f, 0.f, 0.f);
        *(float4*)(out_nk + od)     = z;
        *(float4*)(out_nk + od + 4) = z;
        *(float4*)(out_nv + od)     = z;
        *(float4*)(out_nv + od + 4) = z;
        if (sub == 0) {
            out_nl[(size_t)b * KTOP + cg] = 0.0f;
            out_id[(size_t)b * KTOP + cg] = 0.0f;
        }
    }
}

extern "C" void kernel_launch(void* const* d_in, const int* in_sizes, int n_in,
                              void* d_out, int out_size, void* d_ws, size_t ws_size,
                              hipStream_t stream) {
    const float* query  = (const float*)d_in[0];
    const float* keys   = (const float*)d_in[1];
    const float* vals   = (const float*)d_in[2];
    const float* labels = (const float*)d_in[3];
    const int* hard_assign   = (const int*)d_in[4];
    const int* cached_groups = (const int*)d_in[5];
    const int* group_sizes   = (const int*)d_in[6];

    const int B = in_sizes[0] / DIMS;
    const int N = in_sizes[1] / DIMS;
    const int P = in_sizes[6];
    const int MAXG = in_sizes[5] / P;
    const int nslice = (MAXG + SLICE - 1) / SLICE;
    const int npair  = (nslice + 1) / 2;

    float* sims  = (float*)d_ws;                                // B*MAXG floats
    int* qcount  = (int*)((char*)d_ws + (size_t)B * MAXG * 4);  // P ints
    int* qlist   = qcount + P;                                  // P*B ints

    bucket_kernel<<<1, 1024, 0, stream>>>(hard_assign, qcount, qlist, B, P);

    score_kernel<<<P * npair, NTHR, 0, stream>>>(
        query, keys, cached_groups, qcount, qlist, sims, B, N, MAXG, nslice, npair);

    topk_gather_kernel<<<B, 256, 0, stream>>>(
        keys, vals, labels, hard_assign, cached_groups, group_sizes, sims,
        (float*)d_out, B, MAXG);
}

// Round 21
// 49.932 us; speedup vs baseline: 1.0430x; 1.0430x over previous
//
#include <hip/hip_runtime.h>

#define DIMS 128
#define KTOP 16
#define SMAX 2048     // max MAXG supported by top-k kernel
#define SLICE 64      // candidates per score block
#define CK 64         // s_keyT row stride in dwords (unpadded; 2-way = free)
#define QT 32         // queries per chunk (one chunk covers cnt<=32)
#define CQ 32         // s_qT row stride in dwords
#define NTHR 256      // 4 waves: 2 stage keys, 2 stage queries, all compute

__device__ __forceinline__ unsigned long long packsim(float v, int g) {
    unsigned u = __float_as_uint(v);
    u = (u & 0x80000000u) ? ~u : (u | 0x80000000u);
    return ((unsigned long long)u << 32) | (unsigned)(0xFFFFFFFFu - (unsigned)g);
}

// ------- Kernel 0: zero + bucket queries, single block (r5-proven) -------
__global__ __launch_bounds__(1024)
void bucket_kernel(const int* __restrict__ hard_assign,
                   int* __restrict__ qcount, int* __restrict__ qlist, int B, int P)
{
    const int t = threadIdx.x;
    for (int i = t; i < P; i += 1024) qcount[i] = 0;
    __syncthreads();
    for (int b = t; b < B; b += 1024) {
        const int p = hard_assign[b];
        const int slot = atomicAdd(&qcount[p], 1);
        qlist[(size_t)p * B + slot] = b;
    }
}

// ---- Kernel 1 (r18-proven BEST): register-tiled GEMM, 32q x 64c per block ----
// 256 threads (4 waves), 2q x 4c per thread. LDS ~49.8 KB -> 2 blocks/CU
// (8 waves/CU). Key staging (waves 0-1, single 16-load batch) || query staging
// (waves 2-3).
__global__ __launch_bounds__(NTHR)
void score_kernel(const float* __restrict__ query,
                  const float* __restrict__ keys,
                  const int*   __restrict__ cached_groups,
                  const int*   __restrict__ qcount,
                  const int*   __restrict__ qlist,
                  float* __restrict__ sims,
                  int B, int N, int MAXG, int nslice)
{
    __shared__ float s_keyT[DIMS * CK];   // 32 KB, [d][c]
    __shared__ float s_qT[DIMS * CQ];     // 16 KB, [d][q]
    __shared__ float s_inv[SLICE];
    __shared__ int   s_g[SLICE];
    __shared__ int   s_qb[QT];

    const int p = blockIdx.x / nslice;
    const int s = blockIdx.x % nslice;
    const int cnt = qcount[p];
    if (cnt == 0) return;

    const int t = threadIdx.x;
    const int base = s * SLICE;
    const int* gp = cached_groups + (size_t)p * MAXG;
    const int* ql = qlist + (size_t)p * B;

    // ---- parallel staging: waves 0-1 keys, waves 2-3 first query chunk ----
    if (t < 128) {
        // keys: 2 threads per candidate row (64 dims each); all 16 b128 loads
        // issued as ONE batch (256 B in flight/thread) -> 1 gather-latency round.
        const int r    = t >> 1;          // candidate 0..63
        const int half = t & 1;           // dim half
        const int cand = (base + r < MAXG) ? gp[base + r] : -1;
        if (half == 0) s_g[r] = cand;
        const int sf = cand < 0 ? 0 : (cand > N - 1 ? N - 1 : cand);
        const float* kr = keys + (size_t)sf * DIMS + half * 64;
        float4 v[16];
        #pragma unroll
        for (int i = 0; i < 16; ++i)
            v[i] = *(const float4*)(kr + i * 4);
        float ks = 0.0f;
        #pragma unroll
        for (int i = 0; i < 16; ++i) {
            const int d = half * 64 + i * 4;
            ks += v[i].x * v[i].x + v[i].y * v[i].y
                + v[i].z * v[i].z + v[i].w * v[i].w;
            s_keyT[(d + 0) * CK + r] = v[i].x;
            s_keyT[(d + 1) * CK + r] = v[i].y;
            s_keyT[(d + 2) * CK + r] = v[i].z;
            s_keyT[(d + 3) * CK + r] = v[i].w;
        }
        ks += __shfl_xor(ks, 1, 64);      // pair-reduce the two halves
        if (half == 0) s_inv[r] = 1.0f / fmaxf(sqrtf(ks), 1e-12f);
    } else {
        // queries: 4 threads per query row (32 dims each), chunk 0
        const int tq   = t - 128;
        const int q    = tq & 31;         // query slot 0..31
        const int dblk = tq >> 5;         // 0..3, 32 dims each
        const int sq   = ql[(q < cnt) ? q : (cnt - 1)];   // dup tail, store-masked
        if (dblk == 0) s_qb[q] = sq;
        const float* qr = query + (size_t)sq * DIMS + dblk * 32;
        #pragma unroll
        for (int i = 0; i < 8; ++i) {
            const float4 v = *(const float4*)(qr + i * 4);
            const int d = dblk * 32 + i * 4;
            s_qT[(d + 0) * CQ + q] = v.x;
            s_qT[(d + 1) * CQ + q] = v.y;
            s_qT[(d + 2) * CQ + q] = v.z;
            s_qT[(d + 3) * CQ + q] = v.w;
        }
    }
    __syncthreads();

    const int q0 = (t >> 4) * 2;          // 0,2,..,30
    const int c0 = (t & 15) * 4;          // 0,4,..,60

    for (int qbase = 0; ; ) {
        float acc[2][4];
        #pragma unroll
        for (int a = 0; a < 2; ++a)
            #pragma unroll
            for (int bb = 0; bb < 4; ++bb) acc[a][bb] = 0.0f;

        // A-read: b64 broadcast (4 addrs/wave); B-read: b128 2-way (free)
        #pragma unroll 8
        for (int k = 0; k < DIMS; ++k) {
            const float2 aq = *(const float2*)&s_qT[k * CQ + q0];
            const float4 bk = *(const float4*)&s_keyT[k * CK + c0];
            acc[0][0] += aq.x * bk.x; acc[0][1] += aq.x * bk.y;
            acc[0][2] += aq.x * bk.z; acc[0][3] += aq.x * bk.w;
            acc[1][0] += aq.y * bk.x; acc[1][1] += aq.y * bk.y;
            acc[1][2] += aq.y * bk.z; acc[1][3] += aq.y * bk.w;
        }

        // ---- epilogue: scale by key inv-norm, mask invalid, coalesced f4 ----
        const float4 inv = *(const float4*)&s_inv[c0];
        const int4   gv  = *(const int4*)&s_g[c0];
        #pragma unroll
        for (int qi = 0; qi < 2; ++qi) {
            const int ii = qbase + q0 + qi;
            if (ii < cnt) {
                const int b = s_qb[q0 + qi];
                float4 o;
                o.x = (gv.x >= 0) ? acc[qi][0] * inv.x : -1.0e9f;
                o.y = (gv.y >= 0) ? acc[qi][1] * inv.y : -1.0e9f;
                o.z = (gv.z >= 0) ? acc[qi][2] * inv.z : -1.0e9f;
                o.w = (gv.w >= 0) ? acc[qi][3] * inv.w : -1.0e9f;
                float* dst = sims + (size_t)b * MAXG + base + c0;
                if (base + c0 + 3 < MAXG) {
                    *(float4*)dst = o;
                } else {
                    if (base + c0 + 0 < MAXG) dst[0] = o.x;
                    if (base + c0 + 1 < MAXG) dst[1] = o.y;
                    if (base + c0 + 2 < MAXG) dst[2] = o.z;
                }
            }
        }

        qbase += QT;
        if (qbase >= cnt) break;          // common case: single chunk

        // rare path (cnt > 32): restage next query chunk
        __syncthreads();
        if (t >= 128) {
            const int tq   = t - 128;
            const int q    = tq & 31;
            const int dblk = tq >> 5;
            const int ii   = qbase + q;
            const int sq   = ql[(ii < cnt) ? ii : (cnt - 1)];
            if (dblk == 0) s_qb[q] = sq;
            const float* qr = query + (size_t)sq * DIMS + dblk * 32;
            #pragma unroll
            for (int i = 0; i < 8; ++i) {
                const float4 v = *(const float4*)(qr + i * 4);
                const int d = dblk * 32 + i * 4;
                s_qT[(d + 0) * CQ + q] = v.x;
                s_qT[(d + 1) * CQ + q] = v.y;
                s_qT[(d + 2) * CQ + q] = v.z;
                s_qT[(d + 3) * CQ + q] = v.w;
            }
        }
        __syncthreads();
    }
}

// ---------------- Kernel 2: top-16 per query + output gather ----------------
#define CASW(x,y) { if ((x) < (y)) { const unsigned long long _t = (x); (x) = (y); (y) = _t; } }

__global__ __launch_bounds__(256)
void topk_gather_kernel(const float* __restrict__ keys,
                        const float* __restrict__ vals,
                        const float* __restrict__ labels,
                        const int*   __restrict__ hard_assign,
                        const int*   __restrict__ cached_groups,
                        const int*   __restrict__ group_sizes,
                        const float* __restrict__ sims,
                        float* __restrict__ out,
                        int B, int MAXG)
{
    const int b = blockIdx.x, t = threadIdx.x;
    const int lane = t & 63, w = t >> 6;
    const int sub = t & 15, cg = t >> 4;

    __shared__ unsigned long long s_merge[64];
    __shared__ int s_wing[KTOP];

    const int p = hard_assign[b];
    const int grpsz = group_sizes[p];
    const bool normal = (grpsz >= KTOP);
    const int* gptr = cached_groups + (size_t)p * MAXG;
    const float* simrow = sims + (size_t)b * MAXG;

    // phase A: per-wave top-16 of 512. Lane owns 8 CONSECUTIVE candidates ->
    // 2 x b128 vector loads. Any lane<->slot mapping is valid.
    unsigned long long k0, k1, k2, k3, k4, k5, k6, k7;
    {
        const int g0 = w * (SMAX / 4) + lane * 8;
        if (g0 + 7 < MAXG) {
            const float4 va = *(const float4*)(simrow + g0);
            const float4 vb = *(const float4*)(simrow + g0 + 4);
            k0 = packsim(va.x, g0 + 0); k1 = packsim(va.y, g0 + 1);
            k2 = packsim(va.z, g0 + 2); k3 = packsim(va.w, g0 + 3);
            k4 = packsim(vb.x, g0 + 4); k5 = packsim(vb.y, g0 + 5);
            k6 = packsim(vb.z, g0 + 6); k7 = packsim(vb.w, g0 + 7);
        } else {
            #define LDK(j) packsim((g0 + (j) < MAXG) ? simrow[g0 + (j)] : -3.0e38f, g0 + (j))
            k0 = LDK(0); k1 = LDK(1); k2 = LDK(2); k3 = LDK(3);
            k4 = LDK(4); k5 = LDK(5); k6 = LDK(6); k7 = LDK(7);
            #undef LDK
        }
    }
    // Batcher odd-even mergesort, 19 comparators, descending
    CASW(k0,k1) CASW(k2,k3) CASW(k4,k5) CASW(k6,k7)
    CASW(k0,k2) CASW(k1,k3) CASW(k4,k6) CASW(k5,k7)
    CASW(k1,k2) CASW(k5,k6)
    CASW(k0,k4) CASW(k1,k5) CASW(k2,k6) CASW(k3,k7)
    CASW(k2,k4) CASW(k3,k5)
    CASW(k1,k2) CASW(k3,k4) CASW(k5,k6)

    #pragma unroll 1
    for (int r = 0; r < KTOP; ++r) {
        unsigned long long wm = k0;
        #pragma unroll
        for (int off = 1; off < 64; off <<= 1) {
            const unsigned long long o = __shfl_xor(wm, off, 64);
            wm = (o > wm) ? o : wm;
        }
        if (lane == 0) s_merge[w * KTOP + r] = wm;
        if (k0 == wm) {                  // unique keys -> exactly one winner
            k0 = k1; k1 = k2; k2 = k3; k3 = k4;
            k4 = k5; k5 = k6; k6 = k7; k7 = 0ull;
        }
    }
    __syncthreads();

    // phase B: wave 0 bitonic-sorts the 64 survivors (ascending); rank r at lane 63-r
    if (w == 0) {
        unsigned long long u = s_merge[lane];
        #pragma unroll
        for (int k = 2; k <= 64; k <<= 1) {
            #pragma unroll
            for (int j = k >> 1; j > 0; j >>= 1) {
                const unsigned long long o = __shfl_xor(u, j, 64);
                const bool low = (lane & j) == 0;
                const bool asc = (lane & k) == 0;
                const unsigned long long mn = (u < o) ? u : o;
                const unsigned long long mx = (u < o) ? o : u;
                u = (low == asc) ? mn : mx;
            }
        }
        if (lane >= 64 - KTOP)
            s_wing[63 - lane] = (int)(0xFFFFFFFFu - (unsigned)(u & 0xFFFFFFFFull));
    }
    __syncthreads();

    // outputs: group cg handles winner #cg
    const int g    = s_wing[cg];
    const int cand = gptr[g];
    const int idx  = cand < 0 ? 0 : cand;

    const size_t BK = (size_t)B * KTOP;
    float* out_nk = out;
    float* out_nv = out + BK * DIMS;
    float* out_nl = out + 2 * BK * DIMS;
    float* out_id = out_nl + BK;

    const size_t od = ((size_t)b * KTOP + cg) * DIMS + sub * 8;
    if (normal) {
        const float* kr = keys + (size_t)idx * DIMS + sub * 8;
        const float* vr = vals + (size_t)idx * DIMS + sub * 8;
        *(float4*)(out_nk + od)     = *(const float4*)(kr);
        *(float4*)(out_nk + od + 4) = *(const float4*)(kr + 4);
        *(float4*)(out_nv + od)     = *(const float4*)(vr);
        *(float4*)(out_nv + od + 4) = *(const float4*)(vr + 4);
        if (sub == 0) {
            out_nl[(size_t)b * KTOP + cg] = labels[idx];
            out_id[(size_t)b * KTOP + cg] = (float)idx;
        }
    } else {
        const float4 z = make_float4(0.f, 0.f, 0.f, 0.f);
        *(float4*)(out_nk + od)     = z;
        *(float4*)(out_nk + od + 4) = z;
        *(float4*)(out_nv + od)     = z;
        *(float4*)(out_nv + od + 4) = z;
        if (sub == 0) {
            out_nl[(size_t)b * KTOP + cg] = 0.0f;
            out_id[(size_t)b * KTOP + cg] = 0.0f;
        }
    }
}

extern "C" void kernel_launch(void* const* d_in, const int* in_sizes, int n_in,
                              void* d_out, int out_size, void* d_ws, size_t ws_size,
                              hipStream_t stream) {
    const float* query  = (const float*)d_in[0];
    const float* keys   = (const float*)d_in[1];
    const float* vals   = (const float*)d_in[2];
    const float* labels = (const float*)d_in[3];
    const int* hard_assign   = (const int*)d_in[4];
    const int* cached_groups = (const int*)d_in[5];
    const int* group_sizes   = (const int*)d_in[6];

    const int B = in_sizes[0] / DIMS;
    const int N = in_sizes[1] / DIMS;
    const int P = in_sizes[6];
    const int MAXG = in_sizes[5] / P;
    const int nslice = (MAXG + SLICE - 1) / SLICE;

    float* sims  = (float*)d_ws;                                // B*MAXG floats
    int* qcount  = (int*)((char*)d_ws + (size_t)B * MAXG * 4);  // P ints
    int* qlist   = qcount + P;                                  // P*B ints

    bucket_kernel<<<1, 1024, 0, stream>>>(hard_assign, qcount, qlist, B, P);

    score_kernel<<<P * nslice, NTHR, 0, stream>>>(
        query, keys, cached_groups, qcount, qlist, sims, B, N, MAXG, nslice);

    topk_gather_kernel<<<B, 256, 0, stream>>>(
        keys, vals, labels, hard_assign, cached_groups, group_sizes, sims,
        (float*)d_out, B, MAXG);
}